// Round 14
// baseline (204.000 us; speedup 1.0000x reference)
//
// R14: R13 + (a) redweff fused into kvctx via per-(b,mh) last-block counters
//      (deterministic: fixed reduction order, only the executor varies),
//      (b) qout ph2 k0=0 Weff stage hoisted under softmax. 3 launches.
#include <hip/hip_runtime.h>
#include <hip/hip_bf16.h>
#include <math.h>

#define B 16
#define C 256
#define H 4
#define D 32
#define HID 128
#define O3 384
#define N 4096
#define NSPLIT 32
#define QSCALE 0.17677669529663687f  // 1/sqrt(32)
#define RMS_MUL 16.0f                // sqrt(256)
#define EPS 1e-12f

typedef __attribute__((ext_vector_type(8))) short short8;
typedef __attribute__((ext_vector_type(4))) float f32x4;

#define VM0_BARRIER() asm volatile("s_waitcnt vmcnt(0)\ns_barrier" ::: "memory")

__device__ __forceinline__ ushort f2bf(float f) {
  __hip_bfloat16 h = __float2bfloat16(f);
  return *(ushort*)&h;
}
__device__ __forceinline__ void load_lds16(const void* g, void* l) {
  __builtin_amdgcn_global_load_lds((const __attribute__((address_space(1))) void*)g,
                                   (__attribute__((address_space(3))) void*)l, 16, 0, 0);
}

// ---- merged prep: blocks 0..383 -> wA (+counter zero); 384..2431 -> x prep ----
__global__ __launch_bounds__(256) void k_prep(const float* __restrict__ wqkv,
                                              const float* __restrict__ g,
                                              const float* __restrict__ x,
                                              ushort* __restrict__ wA,
                                              ushort* __restrict__ xbf,
                                              int* __restrict__ counters) {
  __shared__ float red[8][32];
  __shared__ float invs[32];
  int t = threadIdx.x;
  if (blockIdx.x < 384) {
    if (blockIdx.x == 0 && t < 32) counters[t] = 0;
    int idx = blockIdx.x * 256 + t;
    wA[idx] = f2bf(wqkv[idx] * g[idx & (C - 1)]);
    return;
  }
  int id = blockIdx.x - 384;
  int g8 = t >> 5, ln = t & 31;
  int b = id >> 7, n0 = (id & 127) * 32;
  const float* xb = x + (size_t)b * C * N + n0 + ln;
  float v[32];
  float ss = 0.f;
  #pragma unroll
  for (int i = 0; i < 32; ++i) {
    v[i] = xb[(size_t)(g8 * 32 + i) * N];
    ss += v[i] * v[i];
  }
  red[g8][ln] = ss;
  __syncthreads();
  if (t < 32) {
    float tot = 0.f;
    #pragma unroll
    for (int j = 0; j < 8; ++j) tot += red[j][t];
    invs[t] = RMS_MUL / fmaxf(sqrtf(tot), EPS);
  }
  __syncthreads();
  float inv = invs[ln];
  ushort* dst = xbf + ((size_t)(b * N + n0 + ln)) * C + g8 * 32;
  #pragma unroll
  for (int ch = 0; ch < 4; ++ch) {
    union { ushort s[8]; uint4 q; } u;
    #pragma unroll
    for (int j = 0; j < 8; ++j) u.s[j] = f2bf(v[ch * 8 + j] * inv);
    *(uint4*)(dst + ch * 8) = u.q;
  }
}

// ---- K/V GEMM + fused context + last-block redweff (1024 blocks) ----
__global__ __launch_bounds__(256, 4) void k_kvctx(const ushort* __restrict__ A,
                                                  const ushort* __restrict__ Bm,
                                                  const float* __restrict__ wout,
                                                  float* __restrict__ ctxp,
                                                  ushort* __restrict__ Weff,
                                                  int* __restrict__ counters) {
  const int K = 256;
  __shared__ ushort lds[16384];   // A dbuf [0,8192) us; B dbuf [8192,16384); then kvt
  __shared__ int lastflag;
  int bid = blockIdx.x;
  int work = (bid & 7) * 128 + (bid >> 3);
  int mh = work & 1, sl = (work >> 1) & 31, b = work >> 6;
  int t = threadIdx.x;
  int lane = t & 63, w = t >> 6;
  int n0 = sl * 128;
  const ushort* Bb = Bm + ((size_t)b * N + n0) * K;
  f32x4 acc[2][8] = {};

  auto stage = [&](int buf, int k0) {
    #pragma unroll
    for (int i = 0; i < 2; ++i) {
      int c = w * 2 + i;
      int lr = c * 16 + (lane >> 2);
      int gr = mh * 64 + (lr & 63) + ((lr & 64) << 1);
      int col = k0 + (lane & 3) * 8;
      load_lds16(A + (size_t)gr * K + col, lds + buf * 4096 + c * 512);
    }
    #pragma unroll
    for (int i = 0; i < 2; ++i) {
      int c = w * 2 + i;
      int row = c * 16 + (lane >> 2);
      int col = k0 + (lane & 3) * 8;
      load_lds16(Bb + (size_t)row * K + col, lds + 8192 + buf * 4096 + c * 512);
    }
  };

  stage(0, 0);
  VM0_BARRIER();
  #pragma unroll
  for (int ki = 0; ki < 8; ++ki) {
    int cur = ki & 1;
    if (ki < 7) stage(cur ^ 1, (ki + 1) * 32);
    const ushort* Ar = lds + cur * 4096;
    const ushort* Br = lds + 8192 + cur * 4096;
    short8 af[2], bfr[8];
    #pragma unroll
    for (int m = 0; m < 2; ++m)
      af[m] = *(const short8*)&Ar[(w * 32 + m * 16 + (lane & 15)) * 32 + (lane >> 4) * 8];
    #pragma unroll
    for (int nn = 0; nn < 8; ++nn)
      bfr[nn] = *(const short8*)&Br[(nn * 16 + (lane & 15)) * 32 + (lane >> 4) * 8];
    #pragma unroll
    for (int m = 0; m < 2; ++m)
      #pragma unroll
      for (int nn = 0; nn < 8; ++nn)
        acc[m][nn] = __builtin_amdgcn_mfma_f32_16x16x32_bf16(af[m], bfr[nn], acc[m][nn], 0, 0, 0);
    VM0_BARRIER();
  }

  float* cbb = ctxp + (size_t)(sl * 64 + b * 4) * 1056;
  if (w < 2) {
    #pragma unroll
    for (int m = 0; m < 2; ++m)
      #pragma unroll
      for (int nn = 0; nn < 8; ++nn)
        #pragma unroll
        for (int j = 0; j < 4; ++j) acc[m][nn][j] = __expf(acc[m][nn][j]);
    #pragma unroll
    for (int m = 0; m < 2; ++m)
      #pragma unroll
      for (int j = 0; j < 4; ++j) {
        float s = 0.f;
        #pragma unroll
        for (int nn = 0; nn < 8; ++nn) s += acc[m][nn][j];
        s += __shfl_xor(s, 1); s += __shfl_xor(s, 2);
        s += __shfl_xor(s, 4); s += __shfl_xor(s, 8);
        if ((lane & 15) == 0) {
          int lr = w * 32 + m * 16 + (lane >> 4) * 4 + j;
          int h = mh * 2 + (lr >> 5);
          cbb[(size_t)h * 1056 + 1024 + (lr & 31)] = s;
        }
      }
  }
  #pragma unroll
  for (int m = 0; m < 2; ++m)
    #pragma unroll
    for (int nn = 0; nn < 8; ++nn) {
      int lr0 = w * 32 + m * 16 + (lane >> 4) * 4;
      int n = nn * 16 + (lane & 15);
      #pragma unroll
      for (int j = 0; j < 4; ++j) {
        int lr = lr0 + j;
        lds[(lr * 128 + n) ^ ((lr & 7) << 3)] = f2bf(acc[m][nn][j]);
      }
    }
  __syncthreads();
  int hl = w >> 1, eh = w & 1;
  f32x4 cacc[2] = {};
  #pragma unroll
  for (int kk = 0; kk < 4; ++kk) {
    short8 af2[2], bv;
    #pragma unroll
    for (int m = 0; m < 2; ++m) {
      int lrk = hl * 32 + m * 16 + (lane & 15);
      af2[m] = *(const short8*)&lds[(lrk * 128 + kk * 32 + (lane >> 4) * 8) ^ ((lrk & 7) << 3)];
    }
    int lrv = 64 + hl * 32 + eh * 16 + (lane & 15);
    bv = *(const short8*)&lds[(lrv * 128 + kk * 32 + (lane >> 4) * 8) ^ ((lrv & 7) << 3)];
    #pragma unroll
    for (int m = 0; m < 2; ++m)
      cacc[m] = __builtin_amdgcn_mfma_f32_16x16x32_bf16(af2[m], bv, cacc[m], 0, 0, 0);
  }
  int hg = mh * 2 + hl;
  float* cb = ctxp + (size_t)(sl * 64 + b * 4 + hg) * 1056;
  #pragma unroll
  for (int m = 0; m < 2; ++m)
    #pragma unroll
    for (int j = 0; j < 4; ++j) {
      int d = m * 16 + (lane >> 4) * 4 + j;
      int e = eh * 16 + (lane & 15);
      cb[d * 32 + e] = cacc[m][j];
    }

  // ---- last block of group (b, mh) runs redweff for its 2 heads ----
  __threadfence();                           // release: ctxp writes visible
  if (t == 0)
    lastflag = (atomicAdd(&counters[b * 2 + mh], 1) == 31);
  __syncthreads();
  if (lastflag) {
    __threadfence();                         // acquire: see all group writes
    float* ctxn = (float*)lds;               // [32][33]
    float* ksum = (float*)lds + 1056;
    int d = t >> 3, e0 = (t & 7) * 4;
    for (int hh = 0; hh < 2; ++hh) {
      int h = mh * 2 + hh;
      int bh = b * 4 + h;
      __syncthreads();                       // LDS reuse across hh
      float vs[4] = {0.f, 0.f, 0.f, 0.f};
      float ks = 0.f;
      for (int s = 0; s < NSPLIT; ++s) {
        const float* cp = ctxp + (size_t)(s * 64 + bh) * 1056;
        f32x4 v = *(const f32x4*)(cp + d * 32 + e0);
        vs[0] += v[0]; vs[1] += v[1]; vs[2] += v[2]; vs[3] += v[3];
        if (t < 32) ks += cp[1024 + t];
      }
      if (t < 32) ksum[t] = ks;
      __syncthreads();
      float rk = 1.f / ksum[d];
      #pragma unroll
      for (int j = 0; j < 4; ++j) ctxn[d * 33 + e0 + j] = vs[j] * rk;
      __syncthreads();
      float wrow[D];
      #pragma unroll
      for (int e = 0; e < D; ++e) wrow[e] = wout[t * HID + h * D + e];
      ushort* wb = Weff + ((size_t)(b * C + t)) * HID + h * D;
      #pragma unroll
      for (int gq = 0; gq < 4; ++gq) {
        union { ushort s[8]; uint4 v; } u;
        #pragma unroll
        for (int dj = 0; dj < 8; ++dj) {
          int dd = gq * 8 + dj;
          float a = 0.f;
          #pragma unroll
          for (int e = 0; e < D; ++e) a += wrow[e] * ctxn[dd * 33 + e];
          u.s[dj] = f2bf(a);
        }
        *(uint4*)(wb + gq * 8) = u.v;
      }
    }
  }
}

// ---- fused q-GEMM (BK=32 dbuf prefetch) + softmax + (Weff x qT) + rmsnorm ----
__global__ __launch_bounds__(256, 4) void k_qout(const ushort* __restrict__ A,
                                                 const ushort* __restrict__ Bm,
                                                 const ushort* __restrict__ WeffG,
                                                 const float* __restrict__ bias,
                                                 const float* __restrict__ g,
                                                 float* __restrict__ outp) {
  const int K = 256;
  __shared__ ushort lds[16384];
  ushort* qlds = lds + 8192;
  int bid = blockIdx.x;
  int work = (bid & 7) * 128 + (bid >> 3);
  int xt = work & 63, b = work >> 6;
  int t = threadIdx.x;
  int lane = t & 63, w = t >> 6;
  int n0 = xt * 64;
  const ushort* Bb = Bm + ((size_t)b * N + n0) * K;
  const ushort* Aw = WeffG + (size_t)b * C * HID;
  ushort* A2buf = lds;                       // ph2 staging, [256][32] per k0

  auto stage2 = [&](int k0) {
    #pragma unroll
    for (int i = 0; i < 4; ++i) {
      int c = w * 4 + i;
      int row = c * 16 + (lane >> 2);
      int col = k0 + (lane & 3) * 8;
      load_lds16(Aw + (size_t)row * HID + col, A2buf + c * 512);
    }
  };

  // ---- phase 1: q GEMM (128 d x 64 n, BK=32 prefetch) + softmax + dump ----
  {
    auto stage1 = [&](int buf, int k0) {
      #pragma unroll
      for (int i = 0; i < 2; ++i) {
        int c = w * 2 + i;
        int row = c * 16 + (lane >> 2);
        int col = k0 + (lane & 3) * 8;
        load_lds16(A + (size_t)row * K + col, lds + buf * 4096 + c * 512);
      }
      {
        int c = w;
        int row = c * 16 + (lane >> 2);
        int col = k0 + (lane & 3) * 8;
        load_lds16(Bb + (size_t)row * K + col, lds + 8192 + buf * 2048 + c * 512);
      }
    };
    f32x4 acc[2][4] = {};
    stage1(0, 0);
    VM0_BARRIER();
    #pragma unroll
    for (int ki = 0; ki < 8; ++ki) {
      int cur = ki & 1;
      if (ki < 7) stage1(cur ^ 1, (ki + 1) * 32);
      const ushort* Ar = lds + cur * 4096;
      const ushort* Br = lds + 8192 + cur * 2048;
      short8 af[2], bfr[4];
      #pragma unroll
      for (int m = 0; m < 2; ++m)
        af[m] = *(const short8*)&Ar[(w * 32 + m * 16 + (lane & 15)) * 32 + (lane >> 4) * 8];
      #pragma unroll
      for (int nn = 0; nn < 4; ++nn)
        bfr[nn] = *(const short8*)&Br[(nn * 16 + (lane & 15)) * 32 + (lane >> 4) * 8];
      #pragma unroll
      for (int m = 0; m < 2; ++m)
        #pragma unroll
        for (int nn = 0; nn < 4; ++nn)
          acc[m][nn] = __builtin_amdgcn_mfma_f32_16x16x32_bf16(af[m], bfr[nn], acc[m][nn], 0, 0, 0);
      VM0_BARRIER();
    }
    // hoist ph2 k0=0 Weff stage under the softmax/dump VALU work
    stage2(0);
    #pragma unroll
    for (int nn = 0; nn < 4; ++nn) {
      float pm = -1e30f;
      #pragma unroll
      for (int m = 0; m < 2; ++m)
        #pragma unroll
        for (int j = 0; j < 4; ++j) pm = fmaxf(pm, acc[m][nn][j]);
      pm = fmaxf(pm, __shfl_xor(pm, 16));
      pm = fmaxf(pm, __shfl_xor(pm, 32));
      float e[2][4], ps = 0.f;
      #pragma unroll
      for (int m = 0; m < 2; ++m)
        #pragma unroll
        for (int j = 0; j < 4; ++j) {
          e[m][j] = __expf(acc[m][nn][j] - pm);
          ps += e[m][j];
        }
      ps += __shfl_xor(ps, 16);
      ps += __shfl_xor(ps, 32);
      float rs = QSCALE / ps;
      #pragma unroll
      for (int m = 0; m < 2; ++m)
        #pragma unroll
        for (int j = 0; j < 4; ++j) acc[m][nn][j] = e[m][j] * rs;
    }
    #pragma unroll
    for (int m = 0; m < 2; ++m)
      #pragma unroll
      for (int nn = 0; nn < 4; ++nn) {
        int d0 = w * 32 + m * 16 + (lane >> 4) * 4;
        int n = nn * 16 + (lane & 15);
        union { ushort us[4]; uint2 v; } u;
        #pragma unroll
        for (int j = 0; j < 4; ++j) u.us[j] = f2bf(acc[m][nn][j]);
        *(uint2*)&qlds[(n * 128 + d0) ^ ((n & 7) << 3)] = u.v;
      }
  }
  __syncthreads();   // full drain: stage2(0) vmcnt + qlds dump visible
  // ---- phase 2: out = Weff[b] (256x128) x qT (64 n), BK=32 ----
  f32x4 acc2[4][4] = {};
  for (int k0 = 0; k0 < HID; k0 += 32) {
    short8 af[4], bfr[4];
    #pragma unroll
    for (int m = 0; m < 4; ++m)
      af[m] = *(const short8*)&A2buf[(w * 64 + m * 16 + (lane & 15)) * 32 + (lane >> 4) * 8];
    #pragma unroll
    for (int nn = 0; nn < 4; ++nn) {
      int n = nn * 16 + (lane & 15);
      bfr[nn] = *(const short8*)&qlds[(n * 128 + k0 + (lane >> 4) * 8) ^ ((n & 7) << 3)];
    }
    #pragma unroll
    for (int m = 0; m < 4; ++m)
      #pragma unroll
      for (int nn = 0; nn < 4; ++nn)
        acc2[m][nn] = __builtin_amdgcn_mfma_f32_16x16x32_bf16(af[m], bfr[nn], acc2[m][nn], 0, 0, 0);
    if (k0 < HID - 32) {
      __syncthreads();                       // all reads of A2buf done
      stage2(k0 + 32);
      VM0_BARRIER();
    }
  }
  // ---- epilogue: bias + per-column rmsnorm + write ----
  __syncthreads();
  float* ssred = (float*)lds;
  #pragma unroll
  for (int m = 0; m < 4; ++m)
    #pragma unroll
    for (int j = 0; j < 4; ++j) {
      int row = w * 64 + m * 16 + (lane >> 4) * 4 + j;
      float bv = bias[row];
      #pragma unroll
      for (int nn = 0; nn < 4; ++nn) acc2[m][nn][j] += bv;
    }
  float ssp[4];
  #pragma unroll
  for (int nn = 0; nn < 4; ++nn) {
    float s = 0.f;
    #pragma unroll
    for (int m = 0; m < 4; ++m)
      #pragma unroll
      for (int j = 0; j < 4; ++j) s += acc2[m][nn][j] * acc2[m][nn][j];
    s += __shfl_xor(s, 16);
    s += __shfl_xor(s, 32);
    ssp[nn] = s;
  }
  if ((lane >> 4) == 0) {
    #pragma unroll
    for (int nn = 0; nn < 4; ++nn) ssred[w * 64 + nn * 16 + (lane & 15)] = ssp[nn];
  }
  __syncthreads();
  float inv[4];
  #pragma unroll
  for (int nn = 0; nn < 4; ++nn) {
    int col = nn * 16 + (lane & 15);
    float tot = ssred[col] + ssred[64 + col] + ssred[128 + col] + ssred[192 + col];
    inv[nn] = RMS_MUL / fmaxf(sqrtf(tot), EPS);
  }
  float* Cb = outp + (size_t)b * C * N + n0;
  #pragma unroll
  for (int m = 0; m < 4; ++m)
    #pragma unroll
    for (int j = 0; j < 4; ++j) {
      int row = w * 64 + m * 16 + (lane >> 4) * 4 + j;
      float gm = g[row];
      #pragma unroll
      for (int nn = 0; nn < 4; ++nn) {
        int col = nn * 16 + (lane & 15);
        Cb[(size_t)row * N + col] = acc2[m][nn][j] * inv[nn] * gm;
      }
    }
}

extern "C" void kernel_launch(void* const* d_in, const int* in_sizes, int n_in,
                              void* d_out, int out_size, void* d_ws, size_t ws_size,
                              hipStream_t stream) {
  const float* x    = (const float*)d_in[0];
  const float* gn   = (const float*)d_in[1];
  const float* wqkv = (const float*)d_in[2];
  const float* wout = (const float*)d_in[3];
  const float* bout = (const float*)d_in[4];
  const float* gout = (const float*)d_in[5];
  float* out = (float*)d_out;
  float* ws  = (float*)d_ws;

  ushort* xbf     = (ushort*)ws;                 // 32 MB [b][n][c]
  float*  ctxp    = ws + 8388608;                // 8.65 MB
  ushort* Weff    = (ushort*)(ws + 10551296);    // 1 MB
  ushort* wA      = (ushort*)(ws + 10813440);    // 192 KB
  int*    counters = (int*)(ws + 10862592);      // 32 ints

  k_prep <<<2432, 256, 0, stream>>>(wqkv, gn, x, wA, xbf, counters);
  k_kvctx<<<1024, 256, 0, stream>>>(wA + 128 * 256, xbf, wout, ctxp, Weff, counters);
  k_qout <<<1024, 256, 0, stream>>>(wA, xbf, Weff, bout, gout, out);
}

// Round 15
// 84.415 us; speedup vs baseline: 2.4166x; 2.4166x over previous
//
// R15: R13 structure restored (4 launches, separate redweff — R14's fused
//      atomic handoff reverted: stale cross-XCD reads + 8x kvctx slowdown).
//      Kept only R14's safe part: qout ph2 Weff-stage hoist + pipelined ph2.
#include <hip/hip_runtime.h>
#include <hip/hip_bf16.h>
#include <math.h>

#define B 16
#define C 256
#define H 4
#define D 32
#define HID 128
#define O3 384
#define N 4096
#define NSPLIT 32
#define QSCALE 0.17677669529663687f  // 1/sqrt(32)
#define RMS_MUL 16.0f                // sqrt(256)
#define EPS 1e-12f

typedef __attribute__((ext_vector_type(8))) short short8;
typedef __attribute__((ext_vector_type(4))) float f32x4;

#define VM0_BARRIER() asm volatile("s_waitcnt vmcnt(0)\ns_barrier" ::: "memory")

__device__ __forceinline__ ushort f2bf(float f) {
  __hip_bfloat16 h = __float2bfloat16(f);
  return *(ushort*)&h;
}
__device__ __forceinline__ void load_lds16(const void* g, void* l) {
  __builtin_amdgcn_global_load_lds((const __attribute__((address_space(1))) void*)g,
                                   (__attribute__((address_space(3))) void*)l, 16, 0, 0);
}

// ---- merged prep: blocks 0..383 -> wA; blocks 384..2431 -> x rmsnorm+transpose ----
__global__ __launch_bounds__(256) void k_prep(const float* __restrict__ wqkv,
                                              const float* __restrict__ g,
                                              const float* __restrict__ x,
                                              ushort* __restrict__ wA,
                                              ushort* __restrict__ xbf) {
  __shared__ float red[8][32];
  __shared__ float invs[32];
  int t = threadIdx.x;
  if (blockIdx.x < 384) {
    int idx = blockIdx.x * 256 + t;
    wA[idx] = f2bf(wqkv[idx] * g[idx & (C - 1)]);
    return;
  }
  int id = blockIdx.x - 384;
  int g8 = t >> 5, ln = t & 31;
  int b = id >> 7, n0 = (id & 127) * 32;
  const float* xb = x + (size_t)b * C * N + n0 + ln;
  float v[32];
  float ss = 0.f;
  #pragma unroll
  for (int i = 0; i < 32; ++i) {
    v[i] = xb[(size_t)(g8 * 32 + i) * N];
    ss += v[i] * v[i];
  }
  red[g8][ln] = ss;
  __syncthreads();
  if (t < 32) {
    float tot = 0.f;
    #pragma unroll
    for (int j = 0; j < 8; ++j) tot += red[j][t];
    invs[t] = RMS_MUL / fmaxf(sqrtf(tot), EPS);
  }
  __syncthreads();
  float inv = invs[ln];
  ushort* dst = xbf + ((size_t)(b * N + n0 + ln)) * C + g8 * 32;
  #pragma unroll
  for (int ch = 0; ch < 4; ++ch) {
    union { ushort s[8]; uint4 q; } u;
    #pragma unroll
    for (int j = 0; j < 8; ++j) u.s[j] = f2bf(v[ch * 8 + j] * inv);
    *(uint4*)(dst + ch * 8) = u.q;
  }
}

// ---- K/V GEMM + fused context, BK=32 dbuf prefetch (1024 blocks) ----
__global__ __launch_bounds__(256, 4) void k_kvctx(const ushort* __restrict__ A,
                                                  const ushort* __restrict__ Bm,
                                                  float* __restrict__ ctxp) {
  const int K = 256;
  __shared__ ushort lds[16384];   // A dbuf [0,8192) us; B dbuf [8192,16384); then kvt
  int bid = blockIdx.x;
  int work = (bid & 7) * 128 + (bid >> 3);
  int mh = work & 1, sl = (work >> 1) & 31, b = work >> 6;
  int t = threadIdx.x;
  int lane = t & 63, w = t >> 6;
  int n0 = sl * 128;
  const ushort* Bb = Bm + ((size_t)b * N + n0) * K;
  f32x4 acc[2][8] = {};

  auto stage = [&](int buf, int k0) {
    #pragma unroll
    for (int i = 0; i < 2; ++i) {
      int c = w * 2 + i;
      int lr = c * 16 + (lane >> 2);
      int gr = mh * 64 + (lr & 63) + ((lr & 64) << 1);
      int col = k0 + (lane & 3) * 8;
      load_lds16(A + (size_t)gr * K + col, lds + buf * 4096 + c * 512);
    }
    #pragma unroll
    for (int i = 0; i < 2; ++i) {
      int c = w * 2 + i;
      int row = c * 16 + (lane >> 2);
      int col = k0 + (lane & 3) * 8;
      load_lds16(Bb + (size_t)row * K + col, lds + 8192 + buf * 4096 + c * 512);
    }
  };

  stage(0, 0);
  VM0_BARRIER();
  #pragma unroll
  for (int ki = 0; ki < 8; ++ki) {
    int cur = ki & 1;
    if (ki < 7) stage(cur ^ 1, (ki + 1) * 32);
    const ushort* Ar = lds + cur * 4096;
    const ushort* Br = lds + 8192 + cur * 4096;
    short8 af[2], bfr[8];
    #pragma unroll
    for (int m = 0; m < 2; ++m)
      af[m] = *(const short8*)&Ar[(w * 32 + m * 16 + (lane & 15)) * 32 + (lane >> 4) * 8];
    #pragma unroll
    for (int nn = 0; nn < 8; ++nn)
      bfr[nn] = *(const short8*)&Br[(nn * 16 + (lane & 15)) * 32 + (lane >> 4) * 8];
    #pragma unroll
    for (int m = 0; m < 2; ++m)
      #pragma unroll
      for (int nn = 0; nn < 8; ++nn)
        acc[m][nn] = __builtin_amdgcn_mfma_f32_16x16x32_bf16(af[m], bfr[nn], acc[m][nn], 0, 0, 0);
    VM0_BARRIER();
  }

  float* cbb = ctxp + (size_t)(sl * 64 + b * 4) * 1056;
  if (w < 2) {
    #pragma unroll
    for (int m = 0; m < 2; ++m)
      #pragma unroll
      for (int nn = 0; nn < 8; ++nn)
        #pragma unroll
        for (int j = 0; j < 4; ++j) acc[m][nn][j] = __expf(acc[m][nn][j]);
    #pragma unroll
    for (int m = 0; m < 2; ++m)
      #pragma unroll
      for (int j = 0; j < 4; ++j) {
        float s = 0.f;
        #pragma unroll
        for (int nn = 0; nn < 8; ++nn) s += acc[m][nn][j];
        s += __shfl_xor(s, 1); s += __shfl_xor(s, 2);
        s += __shfl_xor(s, 4); s += __shfl_xor(s, 8);
        if ((lane & 15) == 0) {
          int lr = w * 32 + m * 16 + (lane >> 4) * 4 + j;
          int h = mh * 2 + (lr >> 5);
          cbb[(size_t)h * 1056 + 1024 + (lr & 31)] = s;
        }
      }
  }
  #pragma unroll
  for (int m = 0; m < 2; ++m)
    #pragma unroll
    for (int nn = 0; nn < 8; ++nn) {
      int lr0 = w * 32 + m * 16 + (lane >> 4) * 4;
      int n = nn * 16 + (lane & 15);
      #pragma unroll
      for (int j = 0; j < 4; ++j) {
        int lr = lr0 + j;
        lds[(lr * 128 + n) ^ ((lr & 7) << 3)] = f2bf(acc[m][nn][j]);
      }
    }
  __syncthreads();
  int hl = w >> 1, eh = w & 1;
  f32x4 cacc[2] = {};
  #pragma unroll
  for (int kk = 0; kk < 4; ++kk) {
    short8 af2[2], bv;
    #pragma unroll
    for (int m = 0; m < 2; ++m) {
      int lrk = hl * 32 + m * 16 + (lane & 15);
      af2[m] = *(const short8*)&lds[(lrk * 128 + kk * 32 + (lane >> 4) * 8) ^ ((lrk & 7) << 3)];
    }
    int lrv = 64 + hl * 32 + eh * 16 + (lane & 15);
    bv = *(const short8*)&lds[(lrv * 128 + kk * 32 + (lane >> 4) * 8) ^ ((lrv & 7) << 3)];
    #pragma unroll
    for (int m = 0; m < 2; ++m)
      cacc[m] = __builtin_amdgcn_mfma_f32_16x16x32_bf16(af2[m], bv, cacc[m], 0, 0, 0);
  }
  int hg = mh * 2 + hl;
  float* cb = ctxp + (size_t)(sl * 64 + b * 4 + hg) * 1056;
  #pragma unroll
  for (int m = 0; m < 2; ++m)
    #pragma unroll
    for (int j = 0; j < 4; ++j) {
      int d = m * 16 + (lane >> 4) * 4 + j;
      int e = eh * 16 + (lane & 15);
      cb[d * 32 + e] = cacc[m][j];
    }
}

// ---- reduce partials + normalize + Weff build (64 blocks) ----
__global__ __launch_bounds__(256) void k_redweff(const float* __restrict__ ctxp,
                                                 const float* __restrict__ wout,
                                                 ushort* __restrict__ Weff) {
  __shared__ float ctxn[D][D + 1];
  __shared__ float ksum[D];
  int bh = blockIdx.x;
  int b = bh >> 2, h = bh & 3;
  int t = threadIdx.x;
  int d = t >> 3, e0 = (t & 7) * 4;
  float vs[4] = {0.f, 0.f, 0.f, 0.f};
  float ks = 0.f;
  for (int s = 0; s < NSPLIT; ++s) {
    const float* cb = ctxp + (size_t)(s * 64 + bh) * 1056;
    f32x4 v = *(const f32x4*)(cb + d * 32 + e0);
    vs[0] += v[0]; vs[1] += v[1]; vs[2] += v[2]; vs[3] += v[3];
    if (t < 32) ks += cb[1024 + t];
  }
  if (t < 32) ksum[t] = ks;
  __syncthreads();
  float rk = 1.f / ksum[d];
  #pragma unroll
  for (int j = 0; j < 4; ++j) ctxn[d][e0 + j] = vs[j] * rk;
  __syncthreads();
  float wrow[D];
  #pragma unroll
  for (int e = 0; e < D; ++e) wrow[e] = wout[t * HID + h * D + e];
  ushort* wb = Weff + ((size_t)(b * C + t)) * HID + h * D;
  #pragma unroll
  for (int g = 0; g < 4; ++g) {
    union { ushort s[8]; uint4 v; } u;
    #pragma unroll
    for (int dj = 0; dj < 8; ++dj) {
      int dd = g * 8 + dj;
      float a = 0.f;
      #pragma unroll
      for (int e = 0; e < D; ++e) a += wrow[e] * ctxn[dd][e];
      u.s[dj] = f2bf(a);
    }
    *(uint4*)(wb + g * 8) = u.v;
  }
}

// ---- fused q-GEMM (BK=32 dbuf prefetch) + softmax + (Weff x qT) + rmsnorm ----
__global__ __launch_bounds__(256, 4) void k_qout(const ushort* __restrict__ A,
                                                 const ushort* __restrict__ Bm,
                                                 const ushort* __restrict__ WeffG,
                                                 const float* __restrict__ bias,
                                                 const float* __restrict__ g,
                                                 float* __restrict__ outp) {
  const int K = 256;
  __shared__ ushort lds[16384];
  ushort* qlds = lds + 8192;
  int bid = blockIdx.x;
  int work = (bid & 7) * 128 + (bid >> 3);
  int xt = work & 63, b = work >> 6;
  int t = threadIdx.x;
  int lane = t & 63, w = t >> 6;
  int n0 = xt * 64;
  const ushort* Bb = Bm + ((size_t)b * N + n0) * K;
  const ushort* Aw = WeffG + (size_t)b * C * HID;
  ushort* A2buf = lds;                       // ph2 staging, [256][32] per k0

  auto stage2 = [&](int k0) {
    #pragma unroll
    for (int i = 0; i < 4; ++i) {
      int c = w * 4 + i;
      int row = c * 16 + (lane >> 2);
      int col = k0 + (lane & 3) * 8;
      load_lds16(Aw + (size_t)row * HID + col, A2buf + c * 512);
    }
  };

  // ---- phase 1: q GEMM (128 d x 64 n, BK=32 prefetch) + softmax + dump ----
  {
    auto stage1 = [&](int buf, int k0) {
      #pragma unroll
      for (int i = 0; i < 2; ++i) {
        int c = w * 2 + i;
        int row = c * 16 + (lane >> 2);
        int col = k0 + (lane & 3) * 8;
        load_lds16(A + (size_t)row * K + col, lds + buf * 4096 + c * 512);
      }
      {
        int c = w;
        int row = c * 16 + (lane >> 2);
        int col = k0 + (lane & 3) * 8;
        load_lds16(Bb + (size_t)row * K + col, lds + 8192 + buf * 2048 + c * 512);
      }
    };
    f32x4 acc[2][4] = {};
    stage1(0, 0);
    VM0_BARRIER();
    #pragma unroll
    for (int ki = 0; ki < 8; ++ki) {
      int cur = ki & 1;
      if (ki < 7) stage1(cur ^ 1, (ki + 1) * 32);
      const ushort* Ar = lds + cur * 4096;
      const ushort* Br = lds + 8192 + cur * 2048;
      short8 af[2], bfr[4];
      #pragma unroll
      for (int m = 0; m < 2; ++m)
        af[m] = *(const short8*)&Ar[(w * 32 + m * 16 + (lane & 15)) * 32 + (lane >> 4) * 8];
      #pragma unroll
      for (int nn = 0; nn < 4; ++nn)
        bfr[nn] = *(const short8*)&Br[(nn * 16 + (lane & 15)) * 32 + (lane >> 4) * 8];
      #pragma unroll
      for (int m = 0; m < 2; ++m)
        #pragma unroll
        for (int nn = 0; nn < 4; ++nn)
          acc[m][nn] = __builtin_amdgcn_mfma_f32_16x16x32_bf16(af[m], bfr[nn], acc[m][nn], 0, 0, 0);
      VM0_BARRIER();
    }
    // hoist ph2 k0=0 Weff stage (A-staging region dead) under softmax/dump
    stage2(0);
    #pragma unroll
    for (int nn = 0; nn < 4; ++nn) {
      float pm = -1e30f;
      #pragma unroll
      for (int m = 0; m < 2; ++m)
        #pragma unroll
        for (int j = 0; j < 4; ++j) pm = fmaxf(pm, acc[m][nn][j]);
      pm = fmaxf(pm, __shfl_xor(pm, 16));
      pm = fmaxf(pm, __shfl_xor(pm, 32));
      float e[2][4], ps = 0.f;
      #pragma unroll
      for (int m = 0; m < 2; ++m)
        #pragma unroll
        for (int j = 0; j < 4; ++j) {
          e[m][j] = __expf(acc[m][nn][j] - pm);
          ps += e[m][j];
        }
      ps += __shfl_xor(ps, 16);
      ps += __shfl_xor(ps, 32);
      float rs = QSCALE / ps;
      #pragma unroll
      for (int m = 0; m < 2; ++m)
        #pragma unroll
        for (int j = 0; j < 4; ++j) acc[m][nn][j] = e[m][j] * rs;
    }
    #pragma unroll
    for (int m = 0; m < 2; ++m)
      #pragma unroll
      for (int nn = 0; nn < 4; ++nn) {
        int d0 = w * 32 + m * 16 + (lane >> 4) * 4;
        int n = nn * 16 + (lane & 15);
        union { ushort us[4]; uint2 v; } u;
        #pragma unroll
        for (int j = 0; j < 4; ++j) u.us[j] = f2bf(acc[m][nn][j]);
        *(uint2*)&qlds[(n * 128 + d0) ^ ((n & 7) << 3)] = u.v;
      }
  }
  __syncthreads();   // full drain: stage2(0) vmcnt + lgkmcnt + qlds dump visible
  // ---- phase 2: out = Weff[b] (256x128) x qT (64 n), BK=32, pipelined ----
  f32x4 acc2[4][4] = {};
  for (int k0 = 0; k0 < HID; k0 += 32) {
    short8 af[4], bfr[4];
    #pragma unroll
    for (int m = 0; m < 4; ++m)
      af[m] = *(const short8*)&A2buf[(w * 64 + m * 16 + (lane & 15)) * 32 + (lane >> 4) * 8];
    #pragma unroll
    for (int nn = 0; nn < 4; ++nn) {
      int n = nn * 16 + (lane & 15);
      bfr[nn] = *(const short8*)&qlds[(n * 128 + k0 + (lane >> 4) * 8) ^ ((n & 7) << 3)];
    }
    #pragma unroll
    for (int m = 0; m < 4; ++m)
      #pragma unroll
      for (int nn = 0; nn < 4; ++nn)
        acc2[m][nn] = __builtin_amdgcn_mfma_f32_16x16x32_bf16(af[m], bfr[nn], acc2[m][nn], 0, 0, 0);
    if (k0 < HID - 32) {
      __syncthreads();                       // all reads of A2buf done
      stage2(k0 + 32);
      VM0_BARRIER();
    }
  }
  // ---- epilogue: bias + per-column rmsnorm + write ----
  __syncthreads();
  float* ssred = (float*)lds;
  #pragma unroll
  for (int m = 0; m < 4; ++m)
    #pragma unroll
    for (int j = 0; j < 4; ++j) {
      int row = w * 64 + m * 16 + (lane >> 4) * 4 + j;
      float bv = bias[row];
      #pragma unroll
      for (int nn = 0; nn < 4; ++nn) acc2[m][nn][j] += bv;
    }
  float ssp[4];
  #pragma unroll
  for (int nn = 0; nn < 4; ++nn) {
    float s = 0.f;
    #pragma unroll
    for (int m = 0; m < 4; ++m)
      #pragma unroll
      for (int j = 0; j < 4; ++j) s += acc2[m][nn][j] * acc2[m][nn][j];
    s += __shfl_xor(s, 16);
    s += __shfl_xor(s, 32);
    ssp[nn] = s;
  }
  if ((lane >> 4) == 0) {
    #pragma unroll
    for (int nn = 0; nn < 4; ++nn) ssred[w * 64 + nn * 16 + (lane & 15)] = ssp[nn];
  }
  __syncthreads();
  float inv[4];
  #pragma unroll
  for (int nn = 0; nn < 4; ++nn) {
    int col = nn * 16 + (lane & 15);
    float tot = ssred[col] + ssred[64 + col] + ssred[128 + col] + ssred[192 + col];
    inv[nn] = RMS_MUL / fmaxf(sqrtf(tot), EPS);
  }
  float* Cb = outp + (size_t)b * C * N + n0;
  #pragma unroll
  for (int m = 0; m < 4; ++m)
    #pragma unroll
    for (int j = 0; j < 4; ++j) {
      int row = w * 64 + m * 16 + (lane >> 4) * 4 + j;
      float gm = g[row];
      #pragma unroll
      for (int nn = 0; nn < 4; ++nn) {
        int col = nn * 16 + (lane & 15);
        Cb[(size_t)row * N + col] = acc2[m][nn][j] * inv[nn] * gm;
      }
    }
}

extern "C" void kernel_launch(void* const* d_in, const int* in_sizes, int n_in,
                              void* d_out, int out_size, void* d_ws, size_t ws_size,
                              hipStream_t stream) {
  const float* x    = (const float*)d_in[0];
  const float* gn   = (const float*)d_in[1];
  const float* wqkv = (const float*)d_in[2];
  const float* wout = (const float*)d_in[3];
  const float* bout = (const float*)d_in[4];
  const float* gout = (const float*)d_in[5];
  float* out = (float*)d_out;
  float* ws  = (float*)d_ws;

  ushort* xbf  = (ushort*)ws;                    // 32 MB [b][n][c]
  float*  ctxp = ws + 8388608;                   // 8.65 MB
  ushort* Weff = (ushort*)(ws + 10551296);       // 1 MB
  ushort* wA   = (ushort*)(ws + 10813440);       // 192 KB

  k_prep   <<<2432, 256, 0, stream>>>(wqkv, gn, x, wA, xbf);
  k_kvctx  <<<1024, 256, 0, stream>>>(wA + 128 * 256, xbf, ctxp);
  k_redweff<<<64, 256, 0, stream>>>(ctxp, wout, Weff);
  k_qout   <<<1024, 256, 0, stream>>>(wA, xbf, Weff, bout, gout, out);
}